// Round 2
// baseline (31.071 us; speedup 1.0000x reference)
//
#include <hip/hip_runtime.h>

#define B_ 64
#define N_ 900
#define C_ 16
#define NCHAR_ 75
#define L_ 8

// K1: one thread per (b,n,l). 460800 threads = 7200 waves = 28 waves/CU.
// Lane layout: l fastest (0..7), then n -> consecutive lanes read consecutive
// floats of pred_string_logits => perfectly coalesced 256B/wave-instruction.
__global__ __launch_bounds__(256) void cost_kernel(
    const float* __restrict__ logits,   // [B,N,C]
    const float* __restrict__ boxes,    // [B,N,8]
    const float* __restrict__ ps,       // [B,NCHAR,N,L]
    const float* __restrict__ tgt,      // [B,4]
    const int*   __restrict__ ptype,    // [B]
    const int*   __restrict__ lps,      // [B,L]
    float* __restrict__ cost)           // [B,N]
{
    int tid = blockIdx.x * 256 + threadIdx.x;      // 1800 blocks * 256 = exact
    int l  = tid & 7;
    int bn = tid >> 3;
    int b  = bn / N_;
    int n  = bn - b * N_;
    int lane = threadIdx.x & 63;

    // ---------- string CE: per-lane LSE over 75 chars for one l ----------
    int tl = lps[b * L_ + l];
    const float* p = ps + ((size_t)b * NCHAR_ * N_ + n) * L_ + l;
    float s = 0.0f, tv = 0.0f;
    #pragma unroll
    for (int c = 0; c < NCHAR_; ++c) {
        float v = p[(size_t)c * (N_ * L_)];
        s += __expf(v);
        tv = (c == tl) ? v : tv;
    }
    float part = __logf(s) - tv;
    part += __shfl_xor(part, 1);
    part += __shfl_xor(part, 2);
    part += __shfl_xor(part, 4);
    float cost_string = part * (1.0f / L_);

    // ---------- class cost: 2 logits per lane + shuffle softmax ----------
    float2 xy = ((const float2*)(logits + (size_t)bn * C_))[l];
    float a = xy.x, bvl = xy.y;
    float m = fmaxf(a, bvl);
    m = fmaxf(m, __shfl_xor(m, 1));
    m = fmaxf(m, __shfl_xor(m, 2));
    m = fmaxf(m, __shfl_xor(m, 4));
    float ea = __expf(a - m), eb = __expf(bvl - m);
    float se = ea + eb;
    se += __shfl_xor(se, 1);
    se += __shfl_xor(se, 2);
    se += __shfl_xor(se, 4);
    int tcls = ptype[b];
    float xe = (tcls == 2 * l) ? ea : ((tcls == 2 * l + 1) ? eb : 0.0f);
    xe += __shfl_xor(xe, 1);
    xe += __shfl_xor(xe, 2);
    xe += __shfl_xor(xe, 4);
    float cost_class = -xe / se;

    // ---------- bbox: 1 vertex coord per lane, parity min/max ----------
    float v  = boxes[(size_t)bn * 8 + l];
    float mn = fminf(v, __shfl_xor(v, 2));  mn = fminf(mn, __shfl_xor(mn, 4));
    float mx = fmaxf(v, __shfl_xor(v, 2));  mx = fmaxf(mx, __shfl_xor(mx, 4));
    int grp = lane & ~7;
    float px1 = __shfl(mn, grp + 0);
    float py1 = __shfl(mn, grp + 1);
    float px2 = __shfl(mx, grp + 0);
    float py2 = __shfl(mx, grp + 1);

    float4 tb = *(const float4*)(tgt + b * 4);
    float cost_bbox = fabsf(px1 - tb.x) + fabsf(py1 - tb.y)
                    + fabsf(px2 - tb.z) + fabsf(py2 - tb.w);

    float ltx = fmaxf(px1, tb.x), lty = fmaxf(py1, tb.y);
    float rbx = fminf(px2, tb.z), rby = fminf(py2, tb.w);
    float iw = fmaxf(rbx - ltx, 0.0f), ih = fmaxf(rby - lty, 0.0f);
    float inter = iw * ih;
    float area_p = (px2 - px1) * (py2 - py1);
    float area_t = (tb.z - tb.x) * (tb.w - tb.y);
    float uni = area_p + area_t - inter;
    float iou = inter / uni;
    float cx1 = fminf(px1, tb.x), cy1 = fminf(py1, tb.y);
    float cx2 = fmaxf(px2, tb.z), cy2 = fmaxf(py2, tb.w);
    float cw = fmaxf(cx2 - cx1, 0.0f), ch = fmaxf(cy2 - cy1, 0.0f);
    float area_c = cw * ch;
    float giou = iou - (area_c - uni) / area_c;

    if (l == 0)
        cost[bn] = cost_class + 5.0f * cost_bbox - 2.0f * giou + 10.0f * cost_string;
}

// K2: argmin over N per b with first-index tie-break (jnp.argmin semantics).
__global__ __launch_bounds__(256) void argmin_kernel(
    const float* __restrict__ cost, int* __restrict__ out)
{
    int b = blockIdx.x;
    int t = threadIdx.x;
    const float* cb = cost + b * N_;
    float bv = 3.4e38f;
    int bi = 0;
    for (int n = t; n < N_; n += 256) {
        float v = cb[n];
        if (v < bv) { bv = v; bi = n; }   // strict < keeps earliest within thread
    }
    __shared__ float sv[256];
    __shared__ int   si[256];
    sv[t] = bv; si[t] = bi;
    __syncthreads();
    for (int off = 128; off > 0; off >>= 1) {
        if (t < off) {
            float v2 = sv[t + off]; int i2 = si[t + off];
            if (v2 < sv[t] || (v2 == sv[t] && i2 < si[t])) { sv[t] = v2; si[t] = i2; }
        }
        __syncthreads();
    }
    if (t == 0) out[b] = si[0];
}

extern "C" void kernel_launch(void* const* d_in, const int* in_sizes, int n_in,
                              void* d_out, int out_size, void* d_ws, size_t ws_size,
                              hipStream_t stream) {
    const float* logits = (const float*)d_in[0];   // pred_logits [B,N,C]
    const float* boxes  = (const float*)d_in[1];   // pred_boxes  [B,N,8]
    const float* ps     = (const float*)d_in[2];   // pred_string_logits [B,75,N,8]
    const float* tgt    = (const float*)d_in[3];   // tgt_bboxes [B,4]
    const int*   ptype  = (const int*)d_in[4];     // plate_type [B]
    const int*   lps    = (const int*)d_in[5];     // lps [B,L]

    float* cost = (float*)d_ws;                    // [B,N] = 57600 floats
    int*   out  = (int*)d_out;                     // [B,1] int32

    cost_kernel<<<(B_ * N_ * L_) / 256, 256, 0, stream>>>(
        logits, boxes, ps, tgt, ptype, lps, cost);
    argmin_kernel<<<B_, 256, 0, stream>>>(cost, out);
}

// Round 3
// 30.593 us; speedup vs baseline: 1.0156x; 1.0156x over previous
//
#include <hip/hip_runtime.h>

#define B_ 64
#define N_ 900
#define C_ 16
#define NCHAR_ 75
#define L_ 8

// K1: one thread per (b,n,lpair). 230400 threads = 3600 waves = 14 waves/CU
// (3.5 waves/SIMD). Lane layout: lpair = lane&3, bn = tid>>2 -> a wave's 64
// lanes cover 16 consecutive bn x 4 lpair x 8B = 512B contiguous per
// instruction on the string tensor.
__global__ __launch_bounds__(256) void cost_kernel(
    const float* __restrict__ logits,   // [B,N,C]
    const float* __restrict__ boxes,    // [B,N,8]
    const float* __restrict__ ps,       // [B,NCHAR,N,L]
    const float* __restrict__ tgt,      // [B,4]
    const int*   __restrict__ ptype,    // [B]
    const int*   __restrict__ lps,      // [B,L]
    float* __restrict__ cost)           // [B,N]
{
    int tid   = blockIdx.x * 256 + threadIdx.x;   // 900 blocks * 256 = exact
    int lpair = tid & 3;                          // owns l = 2*lpair, 2*lpair+1
    int bn    = tid >> 2;
    int b     = bn / N_;
    int n     = bn - b * N_;

    // ---------- string CE: per-lane LSE over 75 chars for two l's ----------
    int tl0 = lps[b * L_ + 2 * lpair];
    int tl1 = lps[b * L_ + 2 * lpair + 1];
    const float2* p = (const float2*)(ps + ((size_t)b * NCHAR_ * N_ + n) * L_) + lpair;
    float s0 = 0.0f, s1 = 0.0f, tv0 = 0.0f, tv1 = 0.0f;
    #pragma unroll 5
    for (int c = 0; c < NCHAR_; ++c) {
        float2 v = p[(size_t)c * (N_ * L_ / 2)];
        s0 += __expf(v.x);
        s1 += __expf(v.y);
        tv0 = (c == tl0) ? v.x : tv0;
        tv1 = (c == tl1) ? v.y : tv1;
    }
    float part = __logf(s0) + __logf(s1) - tv0 - tv1;
    part += __shfl_xor(part, 1);
    part += __shfl_xor(part, 2);
    float cost_string = part * (1.0f / L_);

    // ---------- class cost: 4 logits per lane + 4-lane shuffle softmax ----------
    float4 lg = ((const float4*)(logits + (size_t)bn * C_))[lpair];
    float m = fmaxf(fmaxf(lg.x, lg.y), fmaxf(lg.z, lg.w));
    m = fmaxf(m, __shfl_xor(m, 1));
    m = fmaxf(m, __shfl_xor(m, 2));
    float e0 = __expf(lg.x - m), e1 = __expf(lg.y - m);
    float e2 = __expf(lg.z - m), e3 = __expf(lg.w - m);
    float se = (e0 + e1) + (e2 + e3);
    se += __shfl_xor(se, 1);
    se += __shfl_xor(se, 2);
    int tcls = ptype[b];
    int base4 = 4 * lpair;
    float xe = (tcls == base4 + 0) ? e0 : 0.0f;
    xe = (tcls == base4 + 1) ? e1 : xe;
    xe = (tcls == base4 + 2) ? e2 : xe;
    xe = (tcls == base4 + 3) ? e3 : xe;
    xe += __shfl_xor(xe, 1);
    xe += __shfl_xor(xe, 2);
    float cost_class = -xe / se;

    // ---------- bbox: one vertex (x,y) per lane, 4-lane min/max ----------
    float2 w = ((const float2*)(boxes + (size_t)bn * 8))[lpair];
    float px1 = w.x, px2 = w.x, py1 = w.y, py2 = w.y;
    px1 = fminf(px1, __shfl_xor(px1, 1)); px1 = fminf(px1, __shfl_xor(px1, 2));
    px2 = fmaxf(px2, __shfl_xor(px2, 1)); px2 = fmaxf(px2, __shfl_xor(px2, 2));
    py1 = fminf(py1, __shfl_xor(py1, 1)); py1 = fminf(py1, __shfl_xor(py1, 2));
    py2 = fmaxf(py2, __shfl_xor(py2, 1)); py2 = fmaxf(py2, __shfl_xor(py2, 2));

    float4 tb = *(const float4*)(tgt + b * 4);
    float cost_bbox = fabsf(px1 - tb.x) + fabsf(py1 - tb.y)
                    + fabsf(px2 - tb.z) + fabsf(py2 - tb.w);

    float ltx = fmaxf(px1, tb.x), lty = fmaxf(py1, tb.y);
    float rbx = fminf(px2, tb.z), rby = fminf(py2, tb.w);
    float iw = fmaxf(rbx - ltx, 0.0f), ih = fmaxf(rby - lty, 0.0f);
    float inter = iw * ih;
    float area_p = (px2 - px1) * (py2 - py1);
    float area_t = (tb.z - tb.x) * (tb.w - tb.y);
    float uni = area_p + area_t - inter;
    float iou = inter / uni;
    float cx1 = fminf(px1, tb.x), cy1 = fminf(py1, tb.y);
    float cx2 = fmaxf(px2, tb.z), cy2 = fmaxf(py2, tb.w);
    float cw = fmaxf(cx2 - cx1, 0.0f), ch = fmaxf(cy2 - cy1, 0.0f);
    float area_c = cw * ch;
    float giou = iou - (area_c - uni) / area_c;

    if (lpair == 0)
        cost[bn] = cost_class + 5.0f * cost_bbox - 2.0f * giou + 10.0f * cost_string;
}

// K2: argmin over N per b with first-index tie-break (jnp.argmin semantics).
__global__ __launch_bounds__(256) void argmin_kernel(
    const float* __restrict__ cost, int* __restrict__ out)
{
    int b = blockIdx.x;
    int t = threadIdx.x;
    const float* cb = cost + b * N_;
    float bv = 3.4e38f;
    int bi = 0;
    for (int n = t; n < N_; n += 256) {
        float v = cb[n];
        if (v < bv) { bv = v; bi = n; }   // strict < keeps earliest within thread
    }
    __shared__ float sv[256];
    __shared__ int   si[256];
    sv[t] = bv; si[t] = bi;
    __syncthreads();
    for (int off = 128; off > 0; off >>= 1) {
        if (t < off) {
            float v2 = sv[t + off]; int i2 = si[t + off];
            if (v2 < sv[t] || (v2 == sv[t] && i2 < si[t])) { sv[t] = v2; si[t] = i2; }
        }
        __syncthreads();
    }
    if (t == 0) out[b] = si[0];
}

extern "C" void kernel_launch(void* const* d_in, const int* in_sizes, int n_in,
                              void* d_out, int out_size, void* d_ws, size_t ws_size,
                              hipStream_t stream) {
    const float* logits = (const float*)d_in[0];   // pred_logits [B,N,C]
    const float* boxes  = (const float*)d_in[1];   // pred_boxes  [B,N,8]
    const float* ps     = (const float*)d_in[2];   // pred_string_logits [B,75,N,8]
    const float* tgt    = (const float*)d_in[3];   // tgt_bboxes [B,4]
    const int*   ptype  = (const int*)d_in[4];     // plate_type [B]
    const int*   lps    = (const int*)d_in[5];     // lps [B,L]

    float* cost = (float*)d_ws;                    // [B,N] = 57600 floats
    int*   out  = (int*)d_out;                     // [B,1] int32

    cost_kernel<<<(B_ * N_ * 4) / 256, 256, 0, stream>>>(
        logits, boxes, ps, tgt, ptype, lps, cost);
    argmin_kernel<<<B_, 256, 0, stream>>>(cost, out);
}